// Round 7
// baseline (72772.504 us; speedup 1.0000x reference)
//
#include <hip/hip_runtime.h>

// ---------------- problem constants ----------------
#define TDEC 200
#define NB   16
#define PRE  256
#define RNN  1024

// ---------------- ws layout (float offsets) ----------------
#define PM_OFF   0u          // pm[16][512][128]  (transposed)
#define INP_OFF  1048576u    // inp[200][16][256]
#define HA_OFF   1867776u    // h_a[2][16][1024]
#define HD_OFF   1900544u    // h_d[2][16][1024]
#define CTX_OFF  1933312u    // ctx[2][16][512]
#define WB_OFF   1949696u    // w[16][512]
#define WC_OFF   1957888u    // wcum[16][512]
#define BAR_OFF  1966080u    // barrier (576 u32 + pad to 1024)
#define PE_OFF   1967104u    // pe[16][512][32]
#define ZLEN_F   99328u      // zero HA..PE start

typedef unsigned long long u64;
typedef float f32x4 __attribute__((ext_vector_type(4)));
union F2u { u64 u; float f[2]; };
union F4u { f32x4 v; float f[4]; };

__device__ __forceinline__ float sigm(float x)   { return 1.0f / (1.0f + __expf(-x)); }
__device__ __forceinline__ float tanh_f(float x) { return 1.0f - 2.0f / (__expf(2.0f * x) + 1.0f); }

__device__ __forceinline__ float ldc4(const float* p) {
    return __hip_atomic_load((float*)p, __ATOMIC_RELAXED, __HIP_MEMORY_SCOPE_AGENT);
}
__device__ __forceinline__ u64 ldc8u(const u64* p) {
    return __hip_atomic_load((u64*)p, __ATOMIC_RELAXED, __HIP_MEMORY_SCOPE_AGENT);
}
__device__ __forceinline__ void stc4(float* p, float v) {
    __hip_atomic_store(p, v, __ATOMIC_RELAXED, __HIP_MEMORY_SCOPE_AGENT);
}

// 4 coherent 16B loads + drain
#define LOAD4P_WAIT0(d0,d1,d2,d3,p0,p1,p2,p3) \
  asm volatile("global_load_dwordx4 %0, %4, off sc0 sc1\n\t" \
               "global_load_dwordx4 %1, %5, off sc0 sc1\n\t" \
               "global_load_dwordx4 %2, %6, off sc0 sc1\n\t" \
               "global_load_dwordx4 %3, %7, off sc0 sc1\n\t" \
               "s_waitcnt vmcnt(0)" \
    : "=&v"(d0),"=&v"(d1),"=&v"(d2),"=&v"(d3) \
    : "v"(p0),"v"(p1),"v"(p2),"v"(p3) : "memory")

// 8 coherent 16B loads from 8 pointers + drain
#define LOAD8P_WAIT0(d0,d1,d2,d3,d4,d5,d6,d7,p0,p1,p2,p3,p4,p5,p6,p7) \
  asm volatile("global_load_dwordx4 %0, %8, off sc0 sc1\n\t" \
               "global_load_dwordx4 %1, %9, off sc0 sc1\n\t" \
               "global_load_dwordx4 %2, %10, off sc0 sc1\n\t" \
               "global_load_dwordx4 %3, %11, off sc0 sc1\n\t" \
               "global_load_dwordx4 %4, %12, off sc0 sc1\n\t" \
               "global_load_dwordx4 %5, %13, off sc0 sc1\n\t" \
               "global_load_dwordx4 %6, %14, off sc0 sc1\n\t" \
               "global_load_dwordx4 %7, %15, off sc0 sc1\n\t" \
               "s_waitcnt vmcnt(0)" \
    : "=&v"(d0),"=&v"(d1),"=&v"(d2),"=&v"(d3),"=&v"(d4),"=&v"(d5),"=&v"(d6),"=&v"(d7) \
    : "v"(p0),"v"(p1),"v"(p2),"v"(p3),"v"(p4),"v"(p5),"v"(p6),"v"(p7) : "memory")

// 8 loads covering 128B from one base + drain
#define LOAD8X16_WAIT0(d0,d1,d2,d3,d4,d5,d6,d7,p) \
  asm volatile("global_load_dwordx4 %0, %8, off sc0 sc1\n\t" \
               "global_load_dwordx4 %1, %8, off offset:16 sc0 sc1\n\t" \
               "global_load_dwordx4 %2, %8, off offset:32 sc0 sc1\n\t" \
               "global_load_dwordx4 %3, %8, off offset:48 sc0 sc1\n\t" \
               "global_load_dwordx4 %4, %8, off offset:64 sc0 sc1\n\t" \
               "global_load_dwordx4 %5, %8, off offset:80 sc0 sc1\n\t" \
               "global_load_dwordx4 %6, %8, off offset:96 sc0 sc1\n\t" \
               "global_load_dwordx4 %7, %8, off offset:112 sc0 sc1\n\t" \
               "s_waitcnt vmcnt(0)" \
    : "=&v"(d0),"=&v"(d1),"=&v"(d2),"=&v"(d3),"=&v"(d4),"=&v"(d5),"=&v"(d6),"=&v"(d7) \
    : "v"(p) : "memory")

// ---- relaxed monotonic 2-level grid barrier (256 blocks) ----
__device__ __forceinline__ void grid_barrier(unsigned* bar, unsigned g)
{
    asm volatile("s_waitcnt vmcnt(0)" ::: "memory");
    __syncthreads();
    if (threadIdx.x == 0) {
        const int leaf = (blockIdx.x & 15) * 32;
        const unsigned tgt = g * 16u + 15u;
        if (__hip_atomic_fetch_add(&bar[leaf], 1u, __ATOMIC_RELAXED, __HIP_MEMORY_SCOPE_AGENT) == tgt) {
            if (__hip_atomic_fetch_add(&bar[512], 1u, __ATOMIC_RELAXED, __HIP_MEMORY_SCOPE_AGENT) == tgt) {
                __hip_atomic_store(&bar[544], g + 1u, __ATOMIC_RELAXED, __HIP_MEMORY_SCOPE_AGENT);
            } else {
                while (__hip_atomic_load(&bar[544], __ATOMIC_RELAXED, __HIP_MEMORY_SCOPE_AGENT) != g + 1u)
                    __builtin_amdgcn_s_sleep(4);
            }
        } else {
            while (__hip_atomic_load(&bar[544], __ATOMIC_RELAXED, __HIP_MEMORY_SCOPE_AGENT) != g + 1u)
                __builtin_amdgcn_s_sleep(4);
        }
    }
    __syncthreads();
}

struct Win { const float* wp; const float* p0; const float* p1; const float* p2; const float* p3; int wrs; };

__device__ __forceinline__ Win resA(int w, int j0r, int l16, int g16,
    const float* awih, const float* awhh, const float* inpT, const float* ctxP, const float* haP)
{
    Win s; const int col = w * 64; const float* ab; int ars;
    if (col < 256)      { ab = inpT + col;         ars = 256;  s.wrs = 768;  s.wp = awih + (size_t)j0r * 768  + col + l16 * 4; }
    else if (col < 768) { ab = ctxP + (col - 256); ars = 512;  s.wrs = 768;  s.wp = awih + (size_t)j0r * 768  + col + l16 * 4; }
    else                { ab = haP + (col - 768);  ars = 1024; s.wrs = 1024; s.wp = awhh + (size_t)j0r * 1024 + (col - 768) + l16 * 4; }
    const float* base = ab + l16 * 4 + g16 * 4 * ars;
    s.p0 = base; s.p1 = base + ars; s.p2 = base + 2 * ars; s.p3 = base + 3 * ars;
    return s;
}

__device__ __forceinline__ Win resD(int w, int j0r, int l16, int g16,
    const float* dwih, const float* dwhh, const float* haP, const float* ctxP, const float* hdP2)
{
    Win s; const int col = w * 64; const float* ab; int ars;
    if (col < 1024)      { ab = haP + col;           ars = 1024; s.wrs = 1536; s.wp = dwih + (size_t)j0r * 1536 + col + l16 * 4; }
    else if (col < 1536) { ab = ctxP + (col - 1024); ars = 512;  s.wrs = 1536; s.wp = dwih + (size_t)j0r * 1536 + col + l16 * 4; }
    else                 { ab = hdP2 + (col - 1536); ars = 1024; s.wrs = 1024; s.wp = dwhh + (size_t)j0r * 1024 + (col - 1536) + l16 * 4; }
    const float* base = ab + l16 * 4 + g16 * 4 * ars;
    s.p0 = base; s.p1 = base + ars; s.p2 = base + 2 * ars; s.p3 = base + 3 * ars;
    return s;
}

__device__ __forceinline__ void fma16(float acc[16][4], const float* wp, int wrs,
                                      float4 a0, float4 a1, float4 a2, float4 a3)
{
    #pragma unroll
    for (int r = 0; r < 16; ++r) {
        const float4 w4 = *(const float4*)(wp + (size_t)((r & 3) * 1024 + (r >> 2)) * wrs);
        acc[r][0] += w4.x * a0.x + w4.y * a0.y + w4.z * a0.z + w4.w * a0.w;
        acc[r][1] += w4.x * a1.x + w4.y * a1.y + w4.z * a1.z + w4.w * a1.w;
        acc[r][2] += w4.x * a2.x + w4.y * a2.y + w4.z * a2.z + w4.w * a2.w;
        acc[r][3] += w4.x * a3.x + w4.y * a3.y + w4.z * a3.z + w4.w * a3.w;
    }
}

// ---------------- precompute: pm[b][tt][f] (transposed) ----------------
__global__ __launch_bounds__(256) void k_pm(const float* __restrict__ mem,
                                            const float* __restrict__ Wm,
                                            float* __restrict__ pm)
{
    const int bid = blockIdx.x;
    const int b = bid >> 5, ch = bid & 31;
    const int tid = threadIdx.x;
    const int tt0 = ch * 16;
    __shared__ float ml[16][512];
    for (int i = tid; i < 16 * 128; i += 256) {
        const int r = i >> 7, c4 = (i & 127) * 4;
        *(float4*)&ml[r][c4] = *(const float4*)(mem + (size_t)(b * 512 + tt0 + r) * 512 + c4);
    }
    __syncthreads();
    const int f = tid & 127, th = tid >> 7;
    float acc[8] = {0, 0, 0, 0, 0, 0, 0, 0};
    const float* wr = Wm + f * 512;
    for (int d = 0; d < 512; d += 4) {
        const float4 w4 = *(const float4*)(wr + d);
        #pragma unroll
        for (int i = 0; i < 8; ++i) {
            const float4 m4 = *(const float4*)&ml[th * 8 + i][d];
            acc[i] += w4.x * m4.x + w4.y * m4.y + w4.z * m4.z + w4.w * m4.w;
        }
    }
    #pragma unroll
    for (int i = 0; i < 8; ++i)
        pm[((size_t)(b * 512 + tt0 + th * 8 + i)) * 128 + f] = acc[i];
}

// ---------------- precompute: prenet ----------------
__global__ __launch_bounds__(256) void k_prenet(const float* __restrict__ di,
                                                const float* __restrict__ W1,
                                                const float* __restrict__ W2,
                                                float* __restrict__ inp)
{
    const int t = blockIdx.x;
    const int tid = threadIdx.x;
    float* inpT = inp + (size_t)t * (NB * PRE);
    if (t == 0) {
        for (int i = tid; i < NB * PRE; i += 256) inpT[i] = 0.0f;
        return;
    }
    const int s = t - 1;
    __shared__ float xs[16][240];
    __shared__ float h1[16][256];
    for (int i = tid; i < 16 * 240; i += 256) {
        const int b = i / 240, j2 = i % 240;
        xs[b][j2] = di[(size_t)b * 48000 + (j2 % 80) * 600 + s * 3 + j2 / 80];
    }
    __syncthreads();
    const int j = tid;
    {
        float acc[16];
        #pragma unroll
        for (int b = 0; b < 16; ++b) acc[b] = 0.0f;
        const float* wr = W1 + j * 240;
        for (int k = 0; k < 240; k += 4) {
            const float4 w4 = *(const float4*)(wr + k);
            #pragma unroll
            for (int b = 0; b < 16; ++b) {
                const float4 x4 = *(const float4*)&xs[b][k];
                acc[b] += w4.x * x4.x + w4.y * x4.y + w4.z * x4.z + w4.w * x4.w;
            }
        }
        #pragma unroll
        for (int b = 0; b < 16; ++b) h1[b][j] = fmaxf(acc[b], 0.0f);
    }
    __syncthreads();
    {
        float acc[16];
        #pragma unroll
        for (int b = 0; b < 16; ++b) acc[b] = 0.0f;
        const float* wr = W2 + j * 256;
        for (int k = 0; k < 256; k += 4) {
            const float4 w4 = *(const float4*)(wr + k);
            #pragma unroll
            for (int b = 0; b < 16; ++b) {
                const float4 x4 = *(const float4*)&h1[b][k];
                acc[b] += w4.x * x4.x + w4.y * x4.y + w4.z * x4.z + w4.w * x4.w;
            }
        }
        #pragma unroll
        for (int b = 0; b < 16; ++b) inpT[b * 256 + j] = fmaxf(acc[b], 0.0f);
    }
}

// ---------------- persistent decoder kernel: 256 blocks x 1024 threads ----------------
__global__ __launch_bounds__(1024, 4) void k_main(
    const float* __restrict__ mem,  const int* __restrict__ mlen,
    const float* __restrict__ awih, const float* __restrict__ awhh,
    const float* __restrict__ abih, const float* __restrict__ abhh,
    const float* __restrict__ dwih, const float* __restrict__ dwhh,
    const float* __restrict__ dbih, const float* __restrict__ dbhh,
    const float* __restrict__ wq,   const float* __restrict__ vat,
    const float* __restrict__ cw,   const float* __restrict__ ldw,
    const float* __restrict__ pjw,  const float* __restrict__ pjb,
    float* __restrict__ ws, float* __restrict__ out)
{
    const int tid  = threadIdx.x;
    const int bid  = blockIdx.x;
    const int wid  = tid >> 6;
    const int lane = tid & 63;
    const int l16  = lane & 15;
    const int g16  = lane >> 4;

    float* pmT  = ws + PM_OFF;
    float* inp  = ws + INP_OFF;
    float* haB  = ws + HA_OFF;
    float* hdB  = ws + HD_OFF;
    float* ctxB = ws + CTX_OFF;
    float* wBf  = ws + WB_OFF;
    float* wcB  = ws + WC_OFF;
    float* peB  = ws + PE_OFF;
    unsigned* bar = (unsigned*)(ws + BAR_OFF);
    float* outMel = out;
    float* outAl  = out + 768000;

    __shared__ float smem[4352];
    unsigned gen = 0;
    float c_reg = 0.0f;   // persistent cell state, owned by tid<128

    const bool isAtt = (bid < 128);
    const int j0 = (isAtt ? bid : bid - 128) * 8;

    for (int t = 0; t <= TDEC; ++t) {
        const float* haP  = haB + ((t + 1) & 1) * (NB * RNN);
        float*       haC  = haB + (t & 1) * (NB * RNN);
        const float* hdP2 = hdB + (t & 1) * (NB * RNN);
        float*       hdW  = hdB + ((t + 1) & 1) * (NB * RNN);
        const float* ctxP = ctxB + ((t + 1) & 1) * (NB * 512);
        float*       ctxC = ctxB + (t & 1) * (NB * 512);
        const float* inpT = inp + (size_t)t * (NB * PRE);

        // ================= P1: attLSTM(t) / decLSTM(t-1) gates =================
        {
            const int rg = wid & 1, ks = wid >> 1;
            const int j0r = j0 + rg * 4;
            const bool act = isAtt ? (t < TDEC) : (t >= 1);
            if (act) {
                float acc[16][4];
                #pragma unroll
                for (int r = 0; r < 16; ++r) { acc[r][0] = 0; acc[r][1] = 0; acc[r][2] = 0; acc[r][3] = 0; }
                float4 A0, A1, A2, A3, A4, A5, A6, A7;
                if (isAtt) {
                    Win w0 = resA(ks,     j0r, l16, g16, awih, awhh, inpT, ctxP, haP);
                    Win w1 = resA(ks + 8, j0r, l16, g16, awih, awhh, inpT, ctxP, haP);
                    LOAD8P_WAIT0(A0, A1, A2, A3, A4, A5, A6, A7,
                                 w0.p0, w0.p1, w0.p2, w0.p3, w1.p0, w1.p1, w1.p2, w1.p3);
                    fma16(acc, w0.wp, w0.wrs, A0, A1, A2, A3);
                    fma16(acc, w1.wp, w1.wrs, A4, A5, A6, A7);
                    if (ks < 4) {
                        Win w2 = resA(ks + 16, j0r, l16, g16, awih, awhh, inpT, ctxP, haP);
                        Win w3 = resA(ks + 24, j0r, l16, g16, awih, awhh, inpT, ctxP, haP);
                        LOAD8P_WAIT0(A0, A1, A2, A3, A4, A5, A6, A7,
                                     w2.p0, w2.p1, w2.p2, w2.p3, w3.p0, w3.p1, w3.p2, w3.p3);
                        fma16(acc, w2.wp, w2.wrs, A0, A1, A2, A3);
                        fma16(acc, w3.wp, w3.wrs, A4, A5, A6, A7);
                    } else {
                        Win w2 = resA(ks + 16, j0r, l16, g16, awih, awhh, inpT, ctxP, haP);
                        LOAD4P_WAIT0(A0, A1, A2, A3, w2.p0, w2.p1, w2.p2, w2.p3);
                        fma16(acc, w2.wp, w2.wrs, A0, A1, A2, A3);
                    }
                } else {
                    Win w0 = resD(ks,      j0r, l16, g16, dwih, dwhh, haP, ctxP, hdP2);
                    Win w1 = resD(ks + 8,  j0r, l16, g16, dwih, dwhh, haP, ctxP, hdP2);
                    LOAD8P_WAIT0(A0, A1, A2, A3, A4, A5, A6, A7,
                                 w0.p0, w0.p1, w0.p2, w0.p3, w1.p0, w1.p1, w1.p2, w1.p3);
                    fma16(acc, w0.wp, w0.wrs, A0, A1, A2, A3);
                    fma16(acc, w1.wp, w1.wrs, A4, A5, A6, A7);
                    Win w2 = resD(ks + 16, j0r, l16, g16, dwih, dwhh, haP, ctxP, hdP2);
                    Win w3 = resD(ks + 24, j0r, l16, g16, dwih, dwhh, haP, ctxP, hdP2);
                    LOAD8P_WAIT0(A0, A1, A2, A3, A4, A5, A6, A7,
                                 w2.p0, w2.p1, w2.p2, w2.p3, w3.p0, w3.p1, w3.p2, w3.p3);
                    fma16(acc, w2.wp, w2.wrs, A0, A1, A2, A3);
                    fma16(acc, w3.wp, w3.wrs, A4, A5, A6, A7);
                    Win w4 = resD(ks + 32, j0r, l16, g16, dwih, dwhh, haP, ctxP, hdP2);
                    LOAD4P_WAIT0(A0, A1, A2, A3, w4.p0, w4.p1, w4.p2, w4.p3);
                    fma16(acc, w4.wp, w4.wrs, A0, A1, A2, A3);
                }
                #pragma unroll
                for (int m = 1; m <= 8; m <<= 1)
                    #pragma unroll
                    for (int r = 0; r < 16; ++r)
                        #pragma unroll
                        for (int b2 = 0; b2 < 4; ++b2)
                            acc[r][b2] += __shfl_xor(acc[r][b2], m, 16);
                if (l16 == 0)
                    #pragma unroll
                    for (int r = 0; r < 16; ++r)
                        #pragma unroll
                        for (int b2 = 0; b2 < 4; ++b2)
                            smem[wid * 256 + r * 16 + g16 * 4 + b2] = acc[r][b2];
            }
            __syncthreads();
            if (act && tid < 128) {
                const int b = tid >> 3, jl = tid & 7;
                const int rg2 = jl >> 2, jq = jl & 3;
                const int j = j0 + jl;
                const float* bih = isAtt ? abih : dbih;
                const float* bhh = isAtt ? abhh : dbhh;
                float g4[4];
                #pragma unroll
                for (int g = 0; g < 4; ++g) {
                    const int r = jq * 4 + g;
                    float sg = 0.0f;
                    #pragma unroll
                    for (int k2 = 0; k2 < 8; ++k2)
                        sg += smem[(k2 * 2 + rg2) * 256 + r * 16 + b];
                    g4[g] = sg + bih[g * 1024 + j] + bhh[g * 1024 + j];
                }
                const float ii = sigm(g4[0]), ff = sigm(g4[1]);
                const float gg = tanh_f(g4[2]), oo = sigm(g4[3]);
                c_reg = ff * c_reg + ii * gg;
                float* hb = isAtt ? haC : hdW;
                stc4(&hb[b * RNN + j], oo * tanh_f(c_reg));
            }
        }
        grid_barrier(bar, gen); ++gen;

        // ================= P2: q-GEMV + conv + energies (tt-split) =================
        if (t < TDEC) {
            const int b2 = bid & 15, ts = bid >> 4;
            float* smemH  = smem;          // [1024]
            float* smemW  = smem + 1024;   // [64]
            float* smemWC = smem + 1088;   // [64]
            float* smemQ  = smem + 1152;   // [128]
            float* smemL  = smem + 1280;   // [32*33]
            // stage
            if (tid < 512) {
                F2u v; v.u = ldc8u((const u64*)(haC + b2 * 1024) + tid);
                smemH[tid * 2] = v.f[0]; smemH[tid * 2 + 1] = v.f[1];
            } else if (tid < 576) {
                const int i = tid - 512;
                if (i < 62) {
                    const int ix = ts * 32 - 15 + i;
                    smemW[i] = (ix >= 0 && ix < 512) ? ldc4(wBf + b2 * 512 + ix) : 0.0f;
                }
            } else if (tid < 640) {
                const int i = tid - 576;
                if (i < 62) {
                    const int ix = ts * 32 - 15 + i;
                    smemWC[i] = (ix >= 0 && ix < 512) ? ldc4(wcB + b2 * 512 + ix) : 0.0f;
                }
            }
            __syncthreads();
            {   // q-GEMV: 16 waves x 8 f each
                const float4 h0 = *(const float4*)&smemH[lane * 4];
                const float4 h1 = *(const float4*)&smemH[lane * 4 + 256];
                const float4 h2 = *(const float4*)&smemH[lane * 4 + 512];
                const float4 h3 = *(const float4*)&smemH[lane * 4 + 768];
                #pragma unroll
                for (int fl = 0; fl < 8; ++fl) {
                    const int f = wid * 8 + fl;
                    const float* wqr = wq + (size_t)f * 1024 + lane * 4;
                    const float4 w0 = *(const float4*)(wqr);
                    const float4 w1 = *(const float4*)(wqr + 256);
                    const float4 w2 = *(const float4*)(wqr + 512);
                    const float4 w3 = *(const float4*)(wqr + 768);
                    float aq = w0.x * h0.x + w0.y * h0.y + w0.z * h0.z + w0.w * h0.w
                             + w1.x * h1.x + w1.y * h1.y + w1.z * h1.z + w1.w * h1.w
                             + w2.x * h2.x + w2.y * h2.y + w2.z * h2.z + w2.w * h2.w
                             + w3.x * h3.x + w3.y * h3.y + w3.z * h3.z + w3.w * h3.w;
                    #pragma unroll
                    for (int m = 1; m <= 32; m <<= 1) aq += __shfl_xor(aq, m, 64);
                    if (lane == 0) smemQ[f] = aq;
                }
            }
            __syncthreads();
            {   // conv: thread = (ttl, ch)
                const int ttl = tid >> 5, ch = tid & 31;
                const float* cwc = cw + ch * 62;
                float a = 0.0f;
                #pragma unroll
                for (int kk = 0; kk < 31; ++kk)
                    a += smemW[ttl + kk] * cwc[kk] + smemWC[ttl + kk] * cwc[31 + kk];
                smemL[ttl * 33 + ch] = a;
            }
            __syncthreads();
            {   // energies: thread = (ttl, fq); 4 f per thread
                const int ttl = tid >> 5, fq = tid & 31;
                const int tt = ts * 32 + ttl;
                const float* lrow = smemL + ttl * 33;
                F4u pm4; pm4.v = __builtin_nontemporal_load(
                    (const f32x4*)(pmT + ((size_t)(b2 * 512 + tt)) * 128 + fq * 4));
                float pes = 0.0f;
                #pragma unroll
                for (int i = 0; i < 4; ++i) {
                    const int f = fq * 4 + i;
                    const float* lw = ldw + f * 32;
                    float pl = 0.0f;
                    #pragma unroll
                    for (int c2 = 0; c2 < 32; ++c2) pl += lrow[c2] * lw[c2];
                    const float x = smemQ[f] + pl + pm4.f[i];
                    pes += vat[f] * tanh_f(x);
                }
                stc4(peB + ((size_t)(b2 * 512 + tt)) * 32 + fq, pes);
            }
        }
        grid_barrier(bar, gen); ++gen;

        // ================= P3: softmax/ctx (0-63) + proj (64-93) =================
        if (bid < 64) {
            if (t < TDEC) {
                const int b3 = bid & 15, dq = bid >> 4;
                float* pl_ = smem;          // [512]
                float* red = smem + 512;    // [17]
                float* psm = smem + 544;    // [1024]
                if (tid < 512) {
                    const int tt = tid;
                    float4 l0, l1, l2, l3, l4, l5, l6, l7;
                    LOAD8X16_WAIT0(l0, l1, l2, l3, l4, l5, l6, l7,
                                   peB + ((size_t)(b3 * 512 + tt)) * 32);
                    float e = l0.x + l0.y + l0.z + l0.w + l1.x + l1.y + l1.z + l1.w
                            + l2.x + l2.y + l2.z + l2.w + l3.x + l3.y + l3.z + l3.w
                            + l4.x + l4.y + l4.z + l4.w + l5.x + l5.y + l5.z + l5.w
                            + l6.x + l6.y + l6.z + l6.w + l7.x + l7.y + l7.z + l7.w;
                    const float p = (tt < mlen[b3]) ? __expf(e) : 0.0f;
                    pl_[tt] = p;
                    float sred = p;
                    #pragma unroll
                    for (int m = 1; m <= 32; m <<= 1) sred += __shfl_xor(sred, m, 64);
                    if (lane == 0) red[wid] = sred;
                }
                __syncthreads();
                if (tid == 0) {
                    float d = 0.0f;
                    #pragma unroll
                    for (int w = 0; w < 8; ++w) d += red[w];
                    red[8] = 1.0f / d;
                }
                __syncthreads();
                const float rd = red[8];
                {   // ctx slice: 8-way row split
                    const int dl = tid & 127, part = tid >> 7;
                    const float* mr = mem + (size_t)b3 * (512 * 512) + dq * 128 + dl;
                    float a = 0.0f;
                    const int r0 = part * 64;
                    for (int r2 = 0; r2 < 64; ++r2)
                        a += pl_[r0 + r2] * __builtin_nontemporal_load(mr + (size_t)(r0 + r2) * 512);
                    psm[dl * 8 + part] = a;
                }
                __syncthreads();
                if (tid < 128) {
                    float a = 0.0f;
                    #pragma unroll
                    for (int p2 = 0; p2 < 8; ++p2) a += psm[tid * 8 + p2];
                    stc4(&ctxC[b3 * 512 + dq * 128 + tid], a * rd);
                }
                if (dq == 0 && tid < 512) {
                    const float wn = pl_[tid] * rd;
                    stc4(&wBf[b3 * 512 + tid], wn);
                    stc4(&wcB[b3 * 512 + tid], ldc4(&wcB[b3 * 512 + tid]) + wn);
                    outAl[(size_t)b3 * (200 * 512) + (size_t)t * 512 + tid] = wn;
                }
            }
        } else if (bid < 94) {
            if (t >= 1) {
                const int jo = (bid - 64) * 8 + (wid >> 1);
                const int bh = wid & 1;
                const float* pwr = pjw + (size_t)jo * 1536 + lane * 4;
                float a[8] = {0, 0, 0, 0, 0, 0, 0, 0};
                #pragma unroll
                for (int pass = 0; pass < 6; ++pass) {
                    const int k = pass * 256 + lane * 4;
                    const float* q[8];
                    #pragma unroll
                    for (int i = 0; i < 8; ++i) {
                        const int b = bh * 8 + i;
                        q[i] = (pass < 4) ? (hdW + b * 1024 + k) : (ctxP + b * 512 + (k - 1024));
                    }
                    float4 c0, c1, c2, c3, c4, c5, c6, c7;
                    LOAD8P_WAIT0(c0, c1, c2, c3, c4, c5, c6, c7,
                                 q[0], q[1], q[2], q[3], q[4], q[5], q[6], q[7]);
                    const float4 w4 = *(const float4*)(pwr + pass * 256);
                    a[0] += w4.x * c0.x + w4.y * c0.y + w4.z * c0.z + w4.w * c0.w;
                    a[1] += w4.x * c1.x + w4.y * c1.y + w4.z * c1.z + w4.w * c1.w;
                    a[2] += w4.x * c2.x + w4.y * c2.y + w4.z * c2.z + w4.w * c2.w;
                    a[3] += w4.x * c3.x + w4.y * c3.y + w4.z * c3.z + w4.w * c3.w;
                    a[4] += w4.x * c4.x + w4.y * c4.y + w4.z * c4.z + w4.w * c4.w;
                    a[5] += w4.x * c5.x + w4.y * c5.y + w4.z * c5.z + w4.w * c5.w;
                    a[6] += w4.x * c6.x + w4.y * c6.y + w4.z * c6.z + w4.w * c6.w;
                    a[7] += w4.x * c7.x + w4.y * c7.y + w4.z * c7.z + w4.w * c7.w;
                }
                #pragma unroll
                for (int i = 0; i < 8; ++i)
                    #pragma unroll
                    for (int m = 1; m <= 32; m <<= 1) a[i] += __shfl_xor(a[i], m, 64);
                if (lane == 0) {
                    const int m_ = jo % 80;
                    const int u = (t - 1) * 3 + jo / 80;
                    const float bv = pjb[jo];
                    #pragma unroll
                    for (int i = 0; i < 8; ++i)
                        outMel[(size_t)(bh * 8 + i) * 48000 + m_ * 600 + u] = a[i] + bv;
                }
            }
        }
        grid_barrier(bar, gen); ++gen;
    }
}

extern "C" void kernel_launch(void* const* d_in, const int* in_sizes, int n_in,
                              void* d_out, int out_size, void* d_ws, size_t ws_size,
                              hipStream_t stream)
{
    (void)in_sizes; (void)n_in; (void)out_size; (void)ws_size;
    const float* mem  = (const float*)d_in[0];
    const float* di   = (const float*)d_in[1];
    const int*   mlen = (const int*)d_in[2];
    const float* pw1  = (const float*)d_in[3];
    const float* pw2  = (const float*)d_in[4];
    const float* awih = (const float*)d_in[5];
    const float* awhh = (const float*)d_in[6];
    const float* abih = (const float*)d_in[7];
    const float* abhh = (const float*)d_in[8];
    const float* dwih = (const float*)d_in[9];
    const float* dwhh = (const float*)d_in[10];
    const float* dbih = (const float*)d_in[11];
    const float* dbhh = (const float*)d_in[12];
    const float* wqp  = (const float*)d_in[13];
    const float* wmp  = (const float*)d_in[14];
    const float* vat  = (const float*)d_in[15];
    const float* cwp  = (const float*)d_in[16];
    const float* ldwp = (const float*)d_in[17];
    const float* pjw  = (const float*)d_in[18];
    const float* pjb  = (const float*)d_in[19];
    float* ws  = (float*)d_ws;
    float* out = (float*)d_out;

    hipMemsetAsync(ws + HA_OFF, 0, ZLEN_F * sizeof(float), stream);
    hipLaunchKernelGGL(k_pm, dim3(512), dim3(256), 0, stream, mem, wmp, ws + PM_OFF);
    hipLaunchKernelGGL(k_prenet, dim3(200), dim3(256), 0, stream, di, pw1, pw2, ws + INP_OFF);

    void* args[] = { (void*)&mem, (void*)&mlen, (void*)&awih, (void*)&awhh,
                     (void*)&abih, (void*)&abhh, (void*)&dwih, (void*)&dwhh,
                     (void*)&dbih, (void*)&dbhh, (void*)&wqp, (void*)&vat,
                     (void*)&cwp, (void*)&ldwp, (void*)&pjw, (void*)&pjb,
                     (void*)&ws, (void*)&out };
    hipLaunchCooperativeKernel((const void*)k_main, dim3(256), dim3(1024), args, 0, stream);
}

// Round 9
// 24657.805 us; speedup vs baseline: 2.9513x; 2.9513x over previous
//
#include <hip/hip_runtime.h>

// ---------------- problem constants ----------------
#define TDEC 200
#define NB   16
#define PRE  256
#define RNN  1024

// ---------------- ws layout (float offsets) ----------------
#define PM_OFF   0u          // pm[16][512][128]  (transposed)
#define INP_OFF  1048576u    // inp[200][16][256]
#define HA_OFF   1867776u    // h_a[2][16][1024]
#define HD_OFF   1900544u    // h_d[2][16][1024]
#define CTX_OFF  1933312u    // ctx[2][16][512]
#define WB_OFF   1949696u    // w[16][512]
#define WC_OFF   1957888u    // wcum[16][512]
#define BAR_OFF  1966080u    // barrier (576 u32 + pad to 1024)
#define PE_OFF   1967104u    // pe[16][512][32]
#define ZLEN_F   99328u      // zero HA..PE start

typedef unsigned long long u64;
typedef float f32x4 __attribute__((ext_vector_type(4)));
union F2u { u64 u; float f[2]; };
union F4u { f32x4 v; float f[4]; };

__device__ __forceinline__ float sigm(float x)   { return 1.0f / (1.0f + __expf(-x)); }
__device__ __forceinline__ float tanh_f(float x) { return 1.0f - 2.0f / (__expf(2.0f * x) + 1.0f); }

__device__ __forceinline__ float ldc4(const float* p) {
    return __hip_atomic_load((float*)p, __ATOMIC_RELAXED, __HIP_MEMORY_SCOPE_AGENT);
}
__device__ __forceinline__ u64 ldc8u(const u64* p) {
    return __hip_atomic_load((u64*)p, __ATOMIC_RELAXED, __HIP_MEMORY_SCOPE_AGENT);
}
__device__ __forceinline__ void stc4(float* p, float v) {
    __hip_atomic_store(p, v, __ATOMIC_RELAXED, __HIP_MEMORY_SCOPE_AGENT);
}

// 4 coherent 16B loads + drain (self-contained)
#define LOAD4P_WAIT0(d0,d1,d2,d3,p0,p1,p2,p3) \
  asm volatile("global_load_dwordx4 %0, %4, off sc0 sc1\n\t" \
               "global_load_dwordx4 %1, %5, off sc0 sc1\n\t" \
               "global_load_dwordx4 %2, %6, off sc0 sc1\n\t" \
               "global_load_dwordx4 %3, %7, off sc0 sc1\n\t" \
               "s_waitcnt vmcnt(0)" \
    : "=&v"(d0),"=&v"(d1),"=&v"(d2),"=&v"(d3) \
    : "v"(p0),"v"(p1),"v"(p2),"v"(p3) : "memory")

// 8 coherent 16B loads from 8 pointers + drain
#define LOAD8P_WAIT0(d0,d1,d2,d3,d4,d5,d6,d7,p0,p1,p2,p3,p4,p5,p6,p7) \
  asm volatile("global_load_dwordx4 %0, %8, off sc0 sc1\n\t" \
               "global_load_dwordx4 %1, %9, off sc0 sc1\n\t" \
               "global_load_dwordx4 %2, %10, off sc0 sc1\n\t" \
               "global_load_dwordx4 %3, %11, off sc0 sc1\n\t" \
               "global_load_dwordx4 %4, %12, off sc0 sc1\n\t" \
               "global_load_dwordx4 %5, %13, off sc0 sc1\n\t" \
               "global_load_dwordx4 %6, %14, off sc0 sc1\n\t" \
               "global_load_dwordx4 %7, %15, off sc0 sc1\n\t" \
               "s_waitcnt vmcnt(0)" \
    : "=&v"(d0),"=&v"(d1),"=&v"(d2),"=&v"(d3),"=&v"(d4),"=&v"(d5),"=&v"(d6),"=&v"(d7) \
    : "v"(p0),"v"(p1),"v"(p2),"v"(p3),"v"(p4),"v"(p5),"v"(p6),"v"(p7) : "memory")

// 8 loads covering 128B from one base + drain
#define LOAD8X16_WAIT0(d0,d1,d2,d3,d4,d5,d6,d7,p) \
  asm volatile("global_load_dwordx4 %0, %8, off sc0 sc1\n\t" \
               "global_load_dwordx4 %1, %8, off offset:16 sc0 sc1\n\t" \
               "global_load_dwordx4 %2, %8, off offset:32 sc0 sc1\n\t" \
               "global_load_dwordx4 %3, %8, off offset:48 sc0 sc1\n\t" \
               "global_load_dwordx4 %4, %8, off offset:64 sc0 sc1\n\t" \
               "global_load_dwordx4 %5, %8, off offset:80 sc0 sc1\n\t" \
               "global_load_dwordx4 %6, %8, off offset:96 sc0 sc1\n\t" \
               "global_load_dwordx4 %7, %8, off offset:112 sc0 sc1\n\t" \
               "s_waitcnt vmcnt(0)" \
    : "=&v"(d0),"=&v"(d1),"=&v"(d2),"=&v"(d3),"=&v"(d4),"=&v"(d5),"=&v"(d6),"=&v"(d7) \
    : "v"(p) : "memory")

// ---- relaxed monotonic 2-level grid barrier (256 blocks: 16 leaves x 16) ----
__device__ __forceinline__ void grid_barrier(unsigned* bar, unsigned g)
{
    asm volatile("s_waitcnt vmcnt(0)" ::: "memory");
    __syncthreads();
    if (threadIdx.x == 0) {
        const int leaf = (blockIdx.x & 15) * 32;
        const unsigned tgt = g * 16u + 15u;
        if (__hip_atomic_fetch_add(&bar[leaf], 1u, __ATOMIC_RELAXED, __HIP_MEMORY_SCOPE_AGENT) == tgt) {
            if (__hip_atomic_fetch_add(&bar[512], 1u, __ATOMIC_RELAXED, __HIP_MEMORY_SCOPE_AGENT) == tgt) {
                __hip_atomic_store(&bar[544], g + 1u, __ATOMIC_RELAXED, __HIP_MEMORY_SCOPE_AGENT);
            } else {
                while (__hip_atomic_load(&bar[544], __ATOMIC_RELAXED, __HIP_MEMORY_SCOPE_AGENT) != g + 1u)
                    __builtin_amdgcn_s_sleep(4);
            }
        } else {
            while (__hip_atomic_load(&bar[544], __ATOMIC_RELAXED, __HIP_MEMORY_SCOPE_AGENT) != g + 1u)
                __builtin_amdgcn_s_sleep(4);
        }
    }
    __syncthreads();
}

__device__ __forceinline__ const float* act_src(bool isAtt, int c, int b,
    const float* inpT, const float* ctxP, const float* haP, const float* hdP2)
{
    if (isAtt) {
        if (c < 256)  return inpT + b * 256 + c;
        if (c < 768)  return ctxP + b * 512 + (c - 256);
        return haP + b * 1024 + (c - 768);
    } else {
        if (c < 1024) return haP + b * 1024 + c;
        if (c < 1536) return ctxP + b * 512 + (c - 1024);
        return hdP2 + b * 1024 + (c - 1536);
    }
}

// ---------------- precompute: pm[b][tt][f] (transposed) ----------------
__global__ __launch_bounds__(256) void k_pm(const float* __restrict__ mem,
                                            const float* __restrict__ Wm,
                                            float* __restrict__ pm)
{
    const int bid = blockIdx.x;
    const int b = bid >> 5, ch = bid & 31;
    const int tid = threadIdx.x;
    const int tt0 = ch * 16;
    __shared__ float ml[16][512];
    for (int i = tid; i < 16 * 128; i += 256) {
        const int r = i >> 7, c4 = (i & 127) * 4;
        *(float4*)&ml[r][c4] = *(const float4*)(mem + (size_t)(b * 512 + tt0 + r) * 512 + c4);
    }
    __syncthreads();
    const int f = tid & 127, th = tid >> 7;
    float acc[8] = {0, 0, 0, 0, 0, 0, 0, 0};
    const float* wr = Wm + f * 512;
    for (int d = 0; d < 512; d += 4) {
        const float4 w4 = *(const float4*)(wr + d);
        #pragma unroll
        for (int i = 0; i < 8; ++i) {
            const float4 m4 = *(const float4*)&ml[th * 8 + i][d];
            acc[i] += w4.x * m4.x + w4.y * m4.y + w4.z * m4.z + w4.w * m4.w;
        }
    }
    #pragma unroll
    for (int i = 0; i < 8; ++i)
        pm[((size_t)(b * 512 + tt0 + th * 8 + i)) * 128 + f] = acc[i];
}

// ---------------- precompute: prenet ----------------
__global__ __launch_bounds__(256) void k_prenet(const float* __restrict__ di,
                                                const float* __restrict__ W1,
                                                const float* __restrict__ W2,
                                                float* __restrict__ inp)
{
    const int t = blockIdx.x;
    const int tid = threadIdx.x;
    float* inpT = inp + (size_t)t * (NB * PRE);
    if (t == 0) {
        for (int i = tid; i < NB * PRE; i += 256) inpT[i] = 0.0f;
        return;
    }
    const int s = t - 1;
    __shared__ float xs[16][240];
    __shared__ float h1[16][256];
    for (int i = tid; i < 16 * 240; i += 256) {
        const int b = i / 240, j2 = i % 240;
        xs[b][j2] = di[(size_t)b * 48000 + (j2 % 80) * 600 + s * 3 + j2 / 80];
    }
    __syncthreads();
    const int j = tid;
    {
        float acc[16];
        #pragma unroll
        for (int b = 0; b < 16; ++b) acc[b] = 0.0f;
        const float* wr = W1 + j * 240;
        for (int k = 0; k < 240; k += 4) {
            const float4 w4 = *(const float4*)(wr + k);
            #pragma unroll
            for (int b = 0; b < 16; ++b) {
                const float4 x4 = *(const float4*)&xs[b][k];
                acc[b] += w4.x * x4.x + w4.y * x4.y + w4.z * x4.z + w4.w * x4.w;
            }
        }
        #pragma unroll
        for (int b = 0; b < 16; ++b) h1[b][j] = fmaxf(acc[b], 0.0f);
    }
    __syncthreads();
    {
        float acc[16];
        #pragma unroll
        for (int b = 0; b < 16; ++b) acc[b] = 0.0f;
        const float* wr = W2 + j * 256;
        for (int k = 0; k < 256; k += 4) {
            const float4 w4 = *(const float4*)(wr + k);
            #pragma unroll
            for (int b = 0; b < 16; ++b) {
                const float4 x4 = *(const float4*)&h1[b][k];
                acc[b] += w4.x * x4.x + w4.y * x4.y + w4.z * x4.z + w4.w * x4.w;
            }
        }
        #pragma unroll
        for (int b = 0; b < 16; ++b) inpT[b * 256 + j] = fmaxf(acc[b], 0.0f);
    }
}

// ---------------- persistent decoder kernel: 256 blocks x 1024 threads ----------------
__global__ __launch_bounds__(1024) void k_main(
    const float* __restrict__ mem,  const int* __restrict__ mlen,
    const float* __restrict__ awih, const float* __restrict__ awhh,
    const float* __restrict__ abih, const float* __restrict__ abhh,
    const float* __restrict__ dwih, const float* __restrict__ dwhh,
    const float* __restrict__ dbih, const float* __restrict__ dbhh,
    const float* __restrict__ wq,   const float* __restrict__ vat,
    const float* __restrict__ cw,   const float* __restrict__ ldw,
    const float* __restrict__ pjw,  const float* __restrict__ pjb,
    float* __restrict__ ws, float* __restrict__ out)
{
    const int tid  = threadIdx.x;
    const int bid  = blockIdx.x;
    const int wid  = tid >> 6;
    const int lane = tid & 63;

    float* pmT  = ws + PM_OFF;
    float* inp  = ws + INP_OFF;
    float* haB  = ws + HA_OFF;
    float* hdB  = ws + HD_OFF;
    float* ctxB = ws + CTX_OFF;
    float* wBf  = ws + WB_OFF;
    float* wcB  = ws + WC_OFF;
    float* peB  = ws + PE_OFF;
    unsigned* bar = (unsigned*)(ws + BAR_OFF);
    float* outMel = out;
    float* outAl  = out + 768000;

    __shared__ float smem[15232];   // 60.9 KB: act chunk [224 col4][68] / P2 / P3 union
    unsigned gen = 0;
    float c_reg = 0.0f;             // persistent cell state, owned by tid<128

    const bool isAtt = (bid < 128);
    const int j0 = (isAtt ? bid : bid - 128) * 8;
    const int jl = wid & 7, ksub = wid >> 3;
    const int jj = j0 + jl;
    const int bb = lane & 15, kq = lane >> 4;

    const float* wih = isAtt ? awih : dwih;
    const float* whh = isAtt ? awhh : dwhh;
    const int wihs = isAtt ? 768 : 1536;
    const int bnd  = wihs;
    size_t rIH[4], rHH[4];
    #pragma unroll
    for (int g = 0; g < 4; ++g) {
        rIH[g] = (size_t)(g * 1024 + jj) * wihs;
        rHH[g] = (size_t)(g * 1024 + jj) * 1024;
    }
    const int K   = isAtt ? 1792 : 2560;
    const int nch = isAtt ? 2 : 3;

    for (int t = 0; t <= TDEC; ++t) {
        const float* haP  = haB + ((t + 1) & 1) * (NB * RNN);
        float*       haC  = haB + (t & 1) * (NB * RNN);
        const float* hdP2 = hdB + (t & 1) * (NB * RNN);
        float*       hdW  = hdB + ((t + 1) & 1) * (NB * RNN);
        const float* ctxP = ctxB + ((t + 1) & 1) * (NB * 512);
        float*       ctxC = ctxB + (t & 1) * (NB * 512);
        const float* inpT = inp + (size_t)t * (NB * PRE);

        // ================= P1: gate GEMV via LDS-staged acts + cached weights =================
        {
            const bool act = isAtt ? (t < TDEC) : (t >= 1);
            if (act) {
                float accg[4] = {0.0f, 0.0f, 0.0f, 0.0f};
                for (int ch = 0; ch < nch; ++ch) {
                    const int c0 = ch * 896;
                    const int span = (K - c0 < 896) ? (K - c0) : 896;
                    const int c4cnt = span >> 2;
                    const int q = (16 * c4cnt) >> 2;
                    if (tid < q) {   // stage chunk: coherent burst -> LDS [col4][68]
                        int fi0 = tid, fi1 = tid + q, fi2 = tid + 2 * q, fi3 = tid + 3 * q;
                        const int b0_ = fi0 / c4cnt, c40 = fi0 - b0_ * c4cnt;
                        const int b1_ = fi1 / c4cnt, c41 = fi1 - b1_ * c4cnt;
                        const int b2_ = fi2 / c4cnt, c42 = fi2 - b2_ * c4cnt;
                        const int b3_ = fi3 / c4cnt, c43 = fi3 - b3_ * c4cnt;
                        const float* s0 = act_src(isAtt, c0 + c40 * 4, b0_, inpT, ctxP, haP, hdP2);
                        const float* s1 = act_src(isAtt, c0 + c41 * 4, b1_, inpT, ctxP, haP, hdP2);
                        const float* s2 = act_src(isAtt, c0 + c42 * 4, b2_, inpT, ctxP, haP, hdP2);
                        const float* s3 = act_src(isAtt, c0 + c43 * 4, b3_, inpT, ctxP, haP, hdP2);
                        float4 v0, v1, v2, v3;
                        LOAD4P_WAIT0(v0, v1, v2, v3, s0, s1, s2, s3);
                        *(float4*)&smem[c40 * 68 + b0_ * 4] = v0;
                        *(float4*)&smem[c41 * 68 + b1_ * 4] = v1;
                        *(float4*)&smem[c42 * 68 + b2_ * 4] = v2;
                        *(float4*)&smem[c43 * 68 + b3_ * 4] = v3;
                    }
                    __syncthreads();
                    {   // compute: wave (jl, ksub) covers ksub-half of this chunk
                        const int half = span >> 1;
                        const int iters = half >> 4;
                        const int cbase = c0 + ksub * half;
                        #pragma unroll 4
                        for (int it = 0; it < iters; ++it) {
                            const int gcb = cbase + it * 16;
                            const int lc4 = ((gcb - c0) >> 2) + kq;
                            const float4 a4 = *(const float4*)&smem[lc4 * 68 + bb * 4];
                            const int gcl = gcb + kq * 4;
                            const bool hh = (gcb >= bnd);
                            #pragma unroll
                            for (int g = 0; g < 4; ++g) {
                                const float* wr = hh ? (whh + rHH[g] + (gcl - bnd))
                                                     : (wih + rIH[g] + gcl);
                                const float4 w4 = *(const float4*)wr;
                                accg[g] += w4.x * a4.x + w4.y * a4.y + w4.z * a4.z + w4.w * a4.w;
                            }
                        }
                    }
                    __syncthreads();
                }
                #pragma unroll
                for (int g = 0; g < 4; ++g) {
                    accg[g] += __shfl_xor(accg[g], 16, 64);
                    accg[g] += __shfl_xor(accg[g], 32, 64);
                }
                if (lane < 16) {
                    #pragma unroll
                    for (int g = 0; g < 4; ++g)
                        smem[ksub * 512 + jl * 64 + g * 16 + lane] = accg[g];
                }
                __syncthreads();
                if (tid < 128) {   // LSTM epilogue: (b, j) per thread
                    const int b = tid >> 3, jb = tid & 7;
                    const int j = j0 + jb;
                    const float* bih = isAtt ? abih : dbih;
                    const float* bhh = isAtt ? abhh : dbhh;
                    float g4[4];
                    #pragma unroll
                    for (int g = 0; g < 4; ++g)
                        g4[g] = smem[jb * 64 + g * 16 + b] + smem[512 + jb * 64 + g * 16 + b]
                              + bih[g * 1024 + j] + bhh[g * 1024 + j];
                    const float ii = sigm(g4[0]), ff = sigm(g4[1]);
                    const float gg = tanh_f(g4[2]), oo = sigm(g4[3]);
                    c_reg = ff * c_reg + ii * gg;
                    float* hb = isAtt ? haC : hdW;
                    stc4(&hb[b * RNN + j], oo * tanh_f(c_reg));
                }
            }
        }
        grid_barrier(bar, gen); ++gen;

        // ================= P2: q-GEMV + conv + energies (32 tt per block) =================
        if (t < TDEC) {
            const int b2 = bid & 15, ts = bid >> 4;   // ts 0..15
            float* smemH  = smem;          // [1024]
            float* smemW  = smem + 1024;   // [62]
            float* smemWC = smem + 1104;   // [62]
            float* smemQ  = smem + 1184;   // [128]
            float* smemL  = smem + 1312;   // [32*33]
            if (tid < 512) {
                F2u v; v.u = ldc8u((const u64*)(haC + b2 * 1024) + tid);
                smemH[tid * 2] = v.f[0]; smemH[tid * 2 + 1] = v.f[1];
            } else if (tid < 574) {
                const int i = tid - 512;
                const int ix = ts * 32 - 15 + i;
                smemW[i] = (ix >= 0 && ix < 512) ? ldc4(wBf + b2 * 512 + ix) : 0.0f;
            } else if (tid < 636) {
                const int i = tid - 574;
                const int ix = ts * 32 - 15 + i;
                smemWC[i] = (ix >= 0 && ix < 512) ? ldc4(wcB + b2 * 512 + ix) : 0.0f;
            }
            __syncthreads();
            {   // q-GEMV: 16 waves x 8 f each
                const float4 h0 = *(const float4*)&smemH[lane * 4];
                const float4 h1 = *(const float4*)&smemH[lane * 4 + 256];
                const float4 h2 = *(const float4*)&smemH[lane * 4 + 512];
                const float4 h3 = *(const float4*)&smemH[lane * 4 + 768];
                #pragma unroll
                for (int fl = 0; fl < 8; ++fl) {
                    const int f = wid * 8 + fl;
                    const float* wqr = wq + (size_t)f * 1024 + lane * 4;
                    const float4 w0 = *(const float4*)(wqr);
                    const float4 w1 = *(const float4*)(wqr + 256);
                    const float4 w2 = *(const float4*)(wqr + 512);
                    const float4 w3 = *(const float4*)(wqr + 768);
                    float aq = w0.x * h0.x + w0.y * h0.y + w0.z * h0.z + w0.w * h0.w
                             + w1.x * h1.x + w1.y * h1.y + w1.z * h1.z + w1.w * h1.w
                             + w2.x * h2.x + w2.y * h2.y + w2.z * h2.z + w2.w * h2.w
                             + w3.x * h3.x + w3.y * h3.y + w3.z * h3.z + w3.w * h3.w;
                    #pragma unroll
                    for (int m = 1; m <= 32; m <<= 1) aq += __shfl_xor(aq, m, 64);
                    if (lane == 0) smemQ[f] = aq;
                }
            }
            __syncthreads();
            {   // conv: thread = (ttl = tid>>5, ch = tid&31)
                const int ttl = tid >> 5, ch = tid & 31;
                const float* cwc = cw + ch * 62;
                float a = 0.0f;
                #pragma unroll
                for (int kk = 0; kk < 31; ++kk)
                    a += smemW[ttl + kk] * cwc[kk] + smemWC[ttl + kk] * cwc[31 + kk];
                smemL[ttl * 33 + ch] = a;
            }
            __syncthreads();
            {   // energies: thread = (ttl, fq); 4 f per thread
                const int ttl = tid >> 5, fq = tid & 31;
                const int tt = ts * 32 + ttl;
                const float* lrow = smemL + ttl * 33;
                F4u pm4; pm4.v = __builtin_nontemporal_load(
                    (const f32x4*)(pmT + ((size_t)(b2 * 512 + tt)) * 128 + fq * 4));
                float pes = 0.0f;
                #pragma unroll
                for (int i = 0; i < 4; ++i) {
                    const int f = fq * 4 + i;
                    const float* lw = ldw + f * 32;
                    float pl = 0.0f;
                    #pragma unroll
                    for (int c2 = 0; c2 < 32; ++c2) pl += lrow[c2] * lw[c2];
                    const float x = smemQ[f] + pl + pm4.f[i];
                    pes += vat[f] * tanh_f(x);
                }
                stc4(peB + ((size_t)(b2 * 512 + tt)) * 32 + fq, pes);
            }
        }
        grid_barrier(bar, gen); ++gen;

        // ================= P3: softmax/ctx (blocks 0-63) + proj (64-93) =================
        if (bid < 64) {
            if (t < TDEC) {
                const int b3 = bid & 15, dq = bid >> 4;
                float* pl_ = smem;          // [512]
                float* red = smem + 512;    // [17]
                float* psm = smem + 544;    // [1024]
                if (tid < 512) {
                    const int tt = tid;
                    float4 l0, l1, l2, l3, l4, l5, l6, l7;
                    LOAD8X16_WAIT0(l0, l1, l2, l3, l4, l5, l6, l7,
                                   peB + ((size_t)(b3 * 512 + tt)) * 32);
                    float e = l0.x + l0.y + l0.z + l0.w + l1.x + l1.y + l1.z + l1.w
                            + l2.x + l2.y + l2.z + l2.w + l3.x + l3.y + l3.z + l3.w
                            + l4.x + l4.y + l4.z + l4.w + l5.x + l5.y + l5.z + l5.w
                            + l6.x + l6.y + l6.z + l6.w + l7.x + l7.y + l7.z + l7.w;
                    const float p = (tt < mlen[b3]) ? __expf(e) : 0.0f;
                    pl_[tt] = p;
                    float sred = p;
                    #pragma unroll
                    for (int m = 1; m <= 32; m <<= 1) sred += __shfl_xor(sred, m, 64);
                    if (lane == 0) red[wid] = sred;
                }
                __syncthreads();
                if (tid == 0) {
                    float d = 0.0f;
                    #pragma unroll
                    for (int w = 0; w < 8; ++w) d += red[w];
                    red[8] = 1.0f / d;
                }
                __syncthreads();
                const float rd = red[8];
                {   // ctx slice: 8-way row split
                    const int dl = tid & 127, part = tid >> 7;
                    const float* mr = mem + (size_t)b3 * (512 * 512) + dq * 128 + dl;
                    float a = 0.0f;
                    const int r0 = part * 64;
                    for (int r2 = 0; r2 < 64; ++r2)
                        a += pl_[r0 + r2] * __builtin_nontemporal_load(mr + (size_t)(r0 + r2) * 512);
                    psm[dl * 8 + part] = a;
                }
                __syncthreads();
                if (tid < 128) {
                    float a = 0.0f;
                    #pragma unroll
                    for (int p2 = 0; p2 < 8; ++p2) a += psm[tid * 8 + p2];
                    stc4(&ctxC[b3 * 512 + dq * 128 + tid], a * rd);
                }
                if (dq == 0 && tid < 512) {
                    const float wn = pl_[tid] * rd;
                    stc4(&wBf[b3 * 512 + tid], wn);
                    stc4(&wcB[b3 * 512 + tid], ldc4(&wcB[b3 * 512 + tid]) + wn);
                    outAl[(size_t)b3 * (200 * 512) + (size_t)t * 512 + tid] = wn;
                }
            }
        } else if (bid < 94) {
            if (t >= 1) {
                const int jo = (bid - 64) * 8 + (wid >> 1);
                const int bh = wid & 1;
                const float* pwr = pjw + (size_t)jo * 1536 + lane * 4;
                float a[8] = {0, 0, 0, 0, 0, 0, 0, 0};
                #pragma unroll
                for (int pass = 0; pass < 6; ++pass) {
                    const int k = pass * 256 + lane * 4;
                    const float* qp[8];
                    #pragma unroll
                    for (int i = 0; i < 8; ++i) {
                        const int b = bh * 8 + i;
                        qp[i] = (pass < 4) ? (hdW + b * 1024 + k) : (ctxP + b * 512 + (k - 1024));
                    }
                    float4 c0, c1, c2, c3, c4, c5, c6, c7;
                    LOAD8P_WAIT0(c0, c1, c2, c3, c4, c5, c6, c7,
                                 qp[0], qp[1], qp[2], qp[3], qp[4], qp[5], qp[6], qp[7]);
                    const float4 w4 = *(const float4*)(pwr + pass * 256);
                    a[0] += w4.x * c0.x + w4.y * c0.y + w4.z * c0.z + w4.w * c0.w;
                    a[1] += w4.x * c1.x + w4.y * c1.y + w4.z * c1.z + w4.w * c1.w;
                    a[2] += w4.x * c2.x + w4.y * c2.y + w4.z * c2.z + w4.w * c2.w;
                    a[3] += w4.x * c3.x + w4.y * c3.y + w4.z * c3.z + w4.w * c3.w;
                    a[4] += w4.x * c4.x + w4.y * c4.y + w4.z * c4.z + w4.w * c4.w;
                    a[5] += w4.x * c5.x + w4.y * c5.y + w4.z * c5.z + w4.w * c5.w;
                    a[6] += w4.x * c6.x + w4.y * c6.y + w4.z * c6.z + w4.w * c6.w;
                    a[7] += w4.x * c7.x + w4.y * c7.y + w4.z * c7.z + w4.w * c7.w;
                }
                #pragma unroll
                for (int i = 0; i < 8; ++i)
                    #pragma unroll
                    for (int m = 1; m <= 32; m <<= 1) a[i] += __shfl_xor(a[i], m, 64);
                if (lane == 0) {
                    const int m_ = jo % 80;
                    const int u = (t - 1) * 3 + jo / 80;
                    const float bv = pjb[jo];
                    #pragma unroll
                    for (int i = 0; i < 8; ++i)
                        outMel[(size_t)(bh * 8 + i) * 48000 + m_ * 600 + u] = a[i] + bv;
                }
            }
        }
        grid_barrier(bar, gen); ++gen;
    }
}

extern "C" void kernel_launch(void* const* d_in, const int* in_sizes, int n_in,
                              void* d_out, int out_size, void* d_ws, size_t ws_size,
                              hipStream_t stream)
{
    (void)in_sizes; (void)n_in; (void)out_size; (void)ws_size;
    const float* mem  = (const float*)d_in[0];
    const float* di   = (const float*)d_in[1];
    const int*   mlen = (const int*)d_in[2];
    const float* pw1  = (const float*)d_in[3];
    const float* pw2  = (const float*)d_in[4];
    const float* awih = (const float*)d_in[5];
    const float* awhh = (const float*)d_in[6];
    const float* abih = (const float*)d_in[7];
    const float* abhh = (const float*)d_in[8];
    const float* dwih = (const float*)d_in[9];
    const float* dwhh = (const float*)d_in[10];
    const float* dbih = (const float*)d_in[11];
    const float* dbhh = (const float*)d_in[12];
    const float* wqp  = (const float*)d_in[13];
    const float* wmp  = (const float*)d_in[14];
    const float* vat  = (const float*)d_in[15];
    const float* cwp  = (const float*)d_in[16];
    const float* ldwp = (const float*)d_in[17];
    const float* pjw  = (const float*)d_in[18];
    const float* pjb  = (const float*)d_in[19];
    float* ws  = (float*)d_ws;
    float* out = (float*)d_out;

    hipMemsetAsync(ws + HA_OFF, 0, ZLEN_F * sizeof(float), stream);
    hipLaunchKernelGGL(k_pm, dim3(512), dim3(256), 0, stream, mem, wmp, ws + PM_OFF);
    hipLaunchKernelGGL(k_prenet, dim3(200), dim3(256), 0, stream, di, pw1, pw2, ws + INP_OFF);

    void* args[] = { (void*)&mem, (void*)&mlen, (void*)&awih, (void*)&awhh,
                     (void*)&abih, (void*)&abhh, (void*)&dwih, (void*)&dwhh,
                     (void*)&dbih, (void*)&dbhh, (void*)&wqp, (void*)&vat,
                     (void*)&cwp, (void*)&ldwp, (void*)&pjw, (void*)&pjb,
                     (void*)&ws, (void*)&out };
    hipLaunchCooperativeKernel((const void*)k_main, dim3(256), dim3(1024), args, 0, stream);
}